// Round 18
// baseline (1365.532 us; speedup 1.0000x reference)
//
#include <hip/hip_runtime.h>
#include <hip/hip_bf16.h>

#define D 128
#define NV 100000
#define NC 100000
#define NN 200000
#define NE 640000

typedef __attribute__((ext_vector_type(4))) float f32x4;
typedef __attribute__((ext_vector_type(8))) short bf16x8;

static __device__ __forceinline__ unsigned short f2b(float f) {
    __hip_bfloat16 h = __float2bfloat16(f);
    union { __hip_bfloat16 h; unsigned short u; } c; c.h = h; return c.u;
}
static __device__ __forceinline__ float b2f(unsigned short b) {
    union { unsigned int u; float f; } c; c.u = ((unsigned int)b) << 16; return c.f;
}

// split 8 fp32 -> hi/lo bf16x8. ALL THREE MFMA products required.
template<bool RELU>
static __device__ __forceinline__ void split8v(const float f[8], bf16x8& ah, bf16x8& al)
{
    union { unsigned short s[8]; bf16x8 v; } ph, pl;
    #pragma unroll
    for (int j = 0; j < 8; ++j) {
        float x = RELU ? fmaxf(f[j], 0.f) : f[j];
        ph.s[j] = f2b(x);
        pl.s[j] = f2b(x - b2f(ph.s[j]));
    }
    ah = ph.v; al = pl.v;
}

union H8 { _Float16 h[8]; uint4 u; };
union H4 { _Float16 h[4]; uint2 u; };

// ------------------------------------------------------------------
// Weight prep -> fragment-major: out[(ks*4+lg)*128 + n][j 0..7]
// per matrix: hi 16384 ushorts | lo 16384.
// 0..2 basis1..3, 3..5 root1..3, 6..9 fc1 slices, 10 var_w2, 11 con_w2
// ------------------------------------------------------------------
struct PrepArgs { const float* src[12]; };

__global__ __launch_bounds__(256, 1) void prep_kernel(PrepArgs a, unsigned short* wt)
{
    const float* W = a.src[blockIdx.y];
    unsigned short* hi = wt + (size_t)blockIdx.y * 32768;
    unsigned short* lo = hi + 16384;
    const int o = blockIdx.x * 1024 + threadIdx.x * 4;
    const int slice = o >> 10;
    const int n     = (o >> 3) & 127;
    const int j0    = o & 7;
    union { unsigned short s[4]; unsigned long long u; } ph, pl;
    #pragma unroll
    for (int i = 0; i < 4; ++i) {
        const int k = slice * 8 + j0 + i;
        const float w = W[k * 128 + n];
        ph.s[i] = f2b(w);
        pl.s[i] = f2b(w - b2f(ph.s[i]));
    }
    *(unsigned long long*)&hi[o] = ph.u;
    *(unsigned long long*)&lo[o] = pl.u;
}

static __device__ __forceinline__ const bf16x8* wfrag(const unsigned short* wt,
                                                      int ks, int lg, int n)
{
    return (const bf16x8*)(wt + (((ks * 4 + lg) * 128) + n) * 8);
}

// LDS tile: pre-split bf16 [rows][128 k], XOR-swizzled.
static __device__ __forceinline__ char* haddr(char* base, int row, int byteoff)
{
    return base + row * 256 + (byteoff ^ ((row & 7) << 4));
}

// write 8 fp16-derived elems (x + optional agg) split into hi/lo LDS
template<bool RELU, bool HASAGG>
static __device__ __forceinline__ void wsplit8(uint4 xv, uint4 gv,
                                               char* hb, char* lb, int srow, int ob0)
{
    H8 a0; a0.u = xv;
    float f[8];
    #pragma unroll
    for (int j = 0; j < 8; ++j) f[j] = (float)a0.h[j];
    if (HASAGG) {
        H8 g0; g0.u = gv;
        #pragma unroll
        for (int j = 0; j < 8; ++j) f[j] += (float)g0.h[j];
    }
    bf16x8 h0, l0;
    split8v<RELU>(f, h0, l0);
    *(bf16x8*)(hb + srow * 256 + ob0) = h0;
    *(bf16x8*)(lb + srow * 256 + ob0) = l0;
}

// ------------------------------------------------------------------
// gemm6: C[M,128](fp16) (+)= op(xin[m]) @ W (+bias)
// AMODE: 0 = x fp16 ; 1 = x+agg fp16 ; 2 = embed fused hidden.
// ------------------------------------------------------------------
template<int AMODE, bool RELU_A, bool ADD_C>
__global__ __launch_bounds__(256, 4) void gemm6(
    const void* A, const _Float16* __restrict__ agg,
    const float* __restrict__ w1, const float* __restrict__ b1, int M,
    const unsigned short* __restrict__ wt, const float* __restrict__ bias,
    _Float16* Cout)
{
    __shared__ unsigned short Hs[2][2][32 * 128];
    const int tid  = threadIdx.x;
    const int lane = tid & 63, wv = tid >> 6;
    const int li   = lane & 15, lg = lane >> 4;
    const int colbase = wv * 32;

    bf16x8 bh[4][2], bl[4][2];
    #pragma unroll
    for (int ks = 0; ks < 4; ++ks)
        #pragma unroll
        for (int nf = 0; nf < 2; ++nf) {
            const int n = colbase + nf * 16 + li;
            bh[ks][nf] = *wfrag(wt,         ks, lg, n);
            bl[ks][nf] = *wfrag(wt + 16384, ks, lg, n);
        }

    const int ntiles = (M + 31) / 32;
    const int G = gridDim.x;
    const int t0 = blockIdx.x;
    if (t0 >= ntiles) return;

    const int srow = tid >> 3;          // 0..31
    const int skf  = (tid & 7) * 16;    // 16 elems / thread
    const int sw   = (srow & 7) << 4;
    const int ob0  = (skf * 2) ^ sw;
    const int ob1  = (skf * 2 + 16) ^ sw;

    #define LOADT(TT, XV0, XV1, GV0, GV1, FV)                                    \
    {                                                                            \
        int grow = (TT) * 32 + srow; if (grow >= M) grow = M - 1;                \
        if (AMODE == 2) {                                                        \
            FV = *(const float2*)((const float*)A + (size_t)grow * 2);           \
        } else {                                                                 \
            const uint4* ap = (const uint4*)((const _Float16*)A + (size_t)grow * D + skf); \
            XV0 = ap[0]; XV1 = ap[1];                                            \
            if (AMODE == 1) {                                                    \
                const uint4* gp = (const uint4*)(agg + (size_t)grow * D + skf);  \
                GV0 = gp[0]; GV1 = gp[1];                                        \
            }                                                                    \
        }                                                                        \
    }
    #define WRITET(BUF, XV0, XV1, GV0, GV1, FV)                                  \
    {                                                                            \
        char* hb_ = (char*)&Hs[BUF][0][0];                                       \
        char* lb_ = (char*)&Hs[BUF][1][0];                                       \
        if (AMODE == 2) {                                                        \
            float f[16];                                                         \
            const float f0 = FV.x, f1 = FV.y;                                    \
            _Pragma("unroll")                                                    \
            for (int q = 0; q < 4; ++q) {                                        \
                const float4 wa = *(const float4*)(w1 + skf + q * 4);            \
                const float4 wb = *(const float4*)(w1 + 128 + skf + q * 4);      \
                const float4 bb = *(const float4*)(b1 + skf + q * 4);            \
                f[q*4+0] = fmaxf(fmaf(f0, wa.x, fmaf(f1, wb.x, bb.x)), 0.f);     \
                f[q*4+1] = fmaxf(fmaf(f0, wa.y, fmaf(f1, wb.y, bb.y)), 0.f);     \
                f[q*4+2] = fmaxf(fmaf(f0, wa.z, fmaf(f1, wb.z, bb.z)), 0.f);     \
                f[q*4+3] = fmaxf(fmaf(f0, wa.w, fmaf(f1, wb.w, bb.w)), 0.f);     \
            }                                                                    \
            bf16x8 h0, l0, h1, l1;                                               \
            split8v<RELU_A>(&f[0], h0, l0);                                     \
            split8v<RELU_A>(&f[8], h1, l1);                                     \
            char* hbr = hb_ + srow * 256; char* lbr = lb_ + srow * 256;          \
            *(bf16x8*)(hbr + ob0) = h0; *(bf16x8*)(hbr + ob1) = h1;              \
            *(bf16x8*)(lbr + ob0) = l0; *(bf16x8*)(lbr + ob1) = l1;              \
        } else {                                                                 \
            wsplit8<RELU_A, AMODE == 1>(XV0, GV0, hb_, lb_, srow, ob0);          \
            wsplit8<RELU_A, AMODE == 1>(XV1, GV1, hb_, lb_, srow, ob1);          \
        }                                                                        \
    }

    {   // prologue
        uint4 xv0 = {0,0,0,0}, xv1 = {0,0,0,0}, gv0 = {0,0,0,0}, gv1 = {0,0,0,0};
        float2 fv = {0, 0};
        LOADT(t0, xv0, xv1, gv0, gv1, fv);
        WRITET(0, xv0, xv1, gv0, gv1, fv);
    }
    __syncthreads();

    int cur = 0;
    for (int t = t0; t < ntiles; t += G) {
        const int tn = t + G;
        const bool pf = tn < ntiles;
        uint4 xv0 = {0,0,0,0}, xv1 = {0,0,0,0}, gv0 = {0,0,0,0}, gv1 = {0,0,0,0};
        float2 fv = {0, 0};
        if (pf) LOADT(tn, xv0, xv1, gv0, gv1, fv);   // EARLY

        char* hb = (char*)&Hs[cur][0][0];
        char* lb = (char*)&Hs[cur][1][0];
        f32x4 acc[2][2];
        #pragma unroll
        for (int ms = 0; ms < 2; ++ms)
            #pragma unroll
            for (int nf = 0; nf < 2; ++nf) acc[ms][nf] = (f32x4){0.f, 0.f, 0.f, 0.f};
        #pragma unroll
        for (int ks = 0; ks < 4; ++ks) {
            const int kb = ks * 64 + lg * 16;
            bf16x8 ah[2], al[2];
            #pragma unroll
            for (int ms = 0; ms < 2; ++ms) {
                const int row = ms * 16 + li;
                ah[ms] = *(const bf16x8*)haddr(hb, row, kb);
                al[ms] = *(const bf16x8*)haddr(lb, row, kb);
            }
            #pragma unroll
            for (int nf = 0; nf < 2; ++nf)
                #pragma unroll
                for (int ms = 0; ms < 2; ++ms) {
                    acc[ms][nf] = __builtin_amdgcn_mfma_f32_16x16x32_bf16(bh[ks][nf], ah[ms], acc[ms][nf], 0, 0, 0);
                    acc[ms][nf] = __builtin_amdgcn_mfma_f32_16x16x32_bf16(bh[ks][nf], al[ms], acc[ms][nf], 0, 0, 0);
                    acc[ms][nf] = __builtin_amdgcn_mfma_f32_16x16x32_bf16(bl[ks][nf], ah[ms], acc[ms][nf], 0, 0, 0);
                }
        }

        #pragma unroll
        for (int ms = 0; ms < 2; ++ms) {
            const int grow = t * 32 + ms * 16 + li;
            if (grow < M) {
                _Float16* crow = Cout + (size_t)grow * D;
                #pragma unroll
                for (int nf = 0; nf < 2; ++nf) {
                    const int c0 = colbase + nf * 16 + lg * 4;
                    float v[4];
                    #pragma unroll
                    for (int r = 0; r < 4; ++r) v[r] = acc[ms][nf][r];
                    if (bias) {
                        const float4 b = *(const float4*)(bias + c0);
                        v[0] += b.x; v[1] += b.y; v[2] += b.z; v[3] += b.w;
                    }
                    if (ADD_C) {
                        H4 rd; rd.u = *(const uint2*)(crow + c0);
                        #pragma unroll
                        for (int r = 0; r < 4; ++r) v[r] += (float)rd.h[r];
                    }
                    H4 pk;
                    #pragma unroll
                    for (int r = 0; r < 4; ++r) pk.h[r] = (_Float16)v[r];
                    *(uint2*)(crow + c0) = pk.u;
                }
            }
        }

        if (pf) WRITET(cur ^ 1, xv0, xv1, gv0, gv1, fv);   // LATE
        __syncthreads();
        cur ^= 1;
    }
    #undef LOADT
    #undef WRITET
}

// ------------------------------------------------------------------
// ugemmf: final fused GEMM. acc = relu(x+agg) @ fc1_3; then
// out[row] += shfl-reduced( relu(acc + u + fc1_b) . fc4_w )  (+fc4_b once)
// Requires d_out zeroed before launch. 4 atomics/row (one per wave).
// ------------------------------------------------------------------
__global__ __launch_bounds__(256, 4) void ugemmf(
    const _Float16* __restrict__ x, const _Float16* __restrict__ agg,
    const _Float16* __restrict__ u, int M,
    const unsigned short* __restrict__ wt,
    const float* __restrict__ fc1_b, const float* __restrict__ fc4_w,
    const float* __restrict__ fc4_b, float* __restrict__ out)
{
    __shared__ unsigned short Hs[2][2][32 * 128];
    const int tid  = threadIdx.x;
    const int lane = tid & 63, wv = tid >> 6;
    const int li   = lane & 15, lg = lane >> 4;
    const int colbase = wv * 32;
    const float fb40 = fc4_b[0];

    bf16x8 bh[4][2], bl[4][2];
    #pragma unroll
    for (int ks = 0; ks < 4; ++ks)
        #pragma unroll
        for (int nf = 0; nf < 2; ++nf) {
            const int n = colbase + nf * 16 + li;
            bh[ks][nf] = *wfrag(wt,         ks, lg, n);
            bl[ks][nf] = *wfrag(wt + 16384, ks, lg, n);
        }

    const int ntiles = (M + 31) / 32;
    const int G = gridDim.x;
    const int t0 = blockIdx.x;
    if (t0 >= ntiles) return;

    const int srow = tid >> 3;
    const int skf  = (tid & 7) * 16;
    const int sw   = (srow & 7) << 4;
    const int ob0  = (skf * 2) ^ sw;
    const int ob1  = (skf * 2 + 16) ^ sw;

    #define LOADU(TT, XV0, XV1, GV0, GV1)                                        \
    {                                                                            \
        int grow = (TT) * 32 + srow; if (grow >= M) grow = M - 1;                \
        const uint4* ap = (const uint4*)(x + (size_t)grow * D + skf);            \
        XV0 = ap[0]; XV1 = ap[1];                                                \
        const uint4* gp = (const uint4*)(agg + (size_t)grow * D + skf);          \
        GV0 = gp[0]; GV1 = gp[1];                                                \
    }

    {   // prologue
        uint4 xv0, xv1, gv0, gv1;
        LOADU(t0, xv0, xv1, gv0, gv1);
        wsplit8<true, true>(xv0, gv0, (char*)&Hs[0][0][0], (char*)&Hs[0][1][0], srow, ob0);
        wsplit8<true, true>(xv1, gv1, (char*)&Hs[0][0][0], (char*)&Hs[0][1][0], srow, ob1);
    }
    __syncthreads();

    int cur = 0;
    for (int t = t0; t < ntiles; t += G) {
        const int tn = t + G;
        const bool pf = tn < ntiles;
        uint4 xv0 = {0,0,0,0}, xv1 = {0,0,0,0}, gv0 = {0,0,0,0}, gv1 = {0,0,0,0};
        if (pf) LOADU(tn, xv0, xv1, gv0, gv1);   // EARLY

        char* hb = (char*)&Hs[cur][0][0];
        char* lb = (char*)&Hs[cur][1][0];
        f32x4 acc[2][2];
        #pragma unroll
        for (int ms = 0; ms < 2; ++ms)
            #pragma unroll
            for (int nf = 0; nf < 2; ++nf) acc[ms][nf] = (f32x4){0.f, 0.f, 0.f, 0.f};
        #pragma unroll
        for (int ks = 0; ks < 4; ++ks) {
            const int kb = ks * 64 + lg * 16;
            bf16x8 ah[2], al[2];
            #pragma unroll
            for (int ms = 0; ms < 2; ++ms) {
                const int row = ms * 16 + li;
                ah[ms] = *(const bf16x8*)haddr(hb, row, kb);
                al[ms] = *(const bf16x8*)haddr(lb, row, kb);
            }
            #pragma unroll
            for (int nf = 0; nf < 2; ++nf)
                #pragma unroll
                for (int ms = 0; ms < 2; ++ms) {
                    acc[ms][nf] = __builtin_amdgcn_mfma_f32_16x16x32_bf16(bh[ks][nf], ah[ms], acc[ms][nf], 0, 0, 0);
                    acc[ms][nf] = __builtin_amdgcn_mfma_f32_16x16x32_bf16(bh[ks][nf], al[ms], acc[ms][nf], 0, 0, 0);
                    acc[ms][nf] = __builtin_amdgcn_mfma_f32_16x16x32_bf16(bl[ks][nf], ah[ms], acc[ms][nf], 0, 0, 0);
                }
        }

        // final epilogue: out[row] += sum_cols relu(acc + u + fc1_b)*fc4_w
        #pragma unroll
        for (int ms = 0; ms < 2; ++ms) {
            const int grow = t * 32 + ms * 16 + li;
            float s = 0.f;
            if (grow < M) {
                const _Float16* urow = u + (size_t)grow * D;
                #pragma unroll
                for (int nf = 0; nf < 2; ++nf) {
                    const int c0 = colbase + nf * 16 + lg * 4;
                    const float4 fb = *(const float4*)(fc1_b + c0);
                    const float4 fw = *(const float4*)(fc4_w + c0);
                    H4 rd; rd.u = *(const uint2*)(urow + c0);
                    const float fbv[4] = {fb.x, fb.y, fb.z, fb.w};
                    const float fwv[4] = {fw.x, fw.y, fw.z, fw.w};
                    #pragma unroll
                    for (int r = 0; r < 4; ++r) {
                        const float v = acc[ms][nf][r] + (float)rd.h[r] + fbv[r];
                        s += fmaxf(v, 0.f) * fwv[r];
                    }
                }
            }
            s += __shfl_xor(s, 16);
            s += __shfl_xor(s, 32);
            if (lg == 0 && grow < M) {
                const float add = s + ((wv == 0) ? fb40 : 0.f);
                atomicAdd(out + grow, add);
            }
        }

        if (pf) {   // LATE
            wsplit8<true, true>(xv0, gv0, (char*)&Hs[cur ^ 1][0][0],
                                (char*)&Hs[cur ^ 1][1][0], srow, ob0);
            wsplit8<true, true>(xv1, gv1, (char*)&Hs[cur ^ 1][0][0],
                                (char*)&Hs[cur ^ 1][1][0], srow, ob1);
        }
        __syncthreads();
        cur ^= 1;
    }
    #undef LOADU
}

// ------------------------------------------------------------------
// layer10: xin = x (+agg) fp16 (shared pre-split LDS tile, 32-row tiles)
// 384 thr = 6 waves: wv0-1 basis (64 cols each), wv2-3 root, wv4-5 u.
// Small blocks -> multiple blocks/CU co-resident; barriers interleave.
// Stagers = threads 0-255 (16 fp16 each); T14 load-early/write-late.
// ------------------------------------------------------------------
template<bool RELU_A, bool HASAGG, bool UADD>
__global__ __launch_bounds__(384, 6) void layer10(
    _Float16* x, const _Float16* __restrict__ agg, int M, int Mroot,
    const unsigned short* __restrict__ wtb, const unsigned short* __restrict__ wtr,
    const unsigned short* __restrict__ wtu, const float* __restrict__ bias,
    unsigned short* __restrict__ y, _Float16* __restrict__ u, int Mu)
{
    __shared__ unsigned short Hs[2][2][32 * 128];
    const int tid  = threadIdx.x;
    const int lane = tid & 63, wv = tid >> 6;      // 0..5
    const int li   = lane & 15, lg = lane >> 4;
    const int wgrp = wv >> 1;                      // 0 basis, 1 root, 2 u
    const int colbase = (wv & 1) * 64;
    const unsigned short* wsel = (wgrp == 0) ? wtb : (wgrp == 1) ? wtr : wtu;

    bf16x8 bh[4][4], bl[4][4];                     // 32 frags = 128 VGPR
    #pragma unroll
    for (int ks = 0; ks < 4; ++ks)
        #pragma unroll
        for (int nf = 0; nf < 4; ++nf) {
            const int n = colbase + nf * 16 + li;
            bh[ks][nf] = *wfrag(wsel,         ks, lg, n);
            bl[ks][nf] = *wfrag(wsel + 16384, ks, lg, n);
        }
    float4 bv[4] = {{0,0,0,0},{0,0,0,0},{0,0,0,0},{0,0,0,0}};
    if (wgrp == 1) {
        #pragma unroll
        for (int nf = 0; nf < 4; ++nf)
            bv[nf] = *(const float4*)(bias + colbase + nf * 16 + lg * 4);
    }

    const int ntiles = (M + 31) / 32;
    const int G = gridDim.x;
    const int t0 = blockIdx.x;
    if (t0 >= ntiles) return;

    const bool stager = tid < 256;
    const int srow = (tid & 255) >> 3;   // 0..31
    const int skf  = (tid & 7) * 16;     // 16 fp16 / thread
    const int sw   = (srow & 7) << 4;
    const int ob0  = (skf * 2) ^ sw;
    const int ob1  = (skf * 2 + 16) ^ sw;

    if (stager) {   // prologue
        int grow = t0 * 32 + srow; if (grow >= M) grow = M - 1;
        const uint4* ap = (const uint4*)(x + (size_t)grow * D + skf);
        uint4 xv0 = ap[0], xv1 = ap[1];
        uint4 gv0 = {0,0,0,0}, gv1 = {0,0,0,0};
        if (HASAGG) {
            const uint4* gp = (const uint4*)(agg + (size_t)grow * D + skf);
            gv0 = gp[0]; gv1 = gp[1];
        }
        wsplit8<RELU_A, HASAGG>(xv0, gv0, (char*)&Hs[0][0][0], (char*)&Hs[0][1][0], srow, ob0);
        wsplit8<RELU_A, HASAGG>(xv1, gv1, (char*)&Hs[0][0][0], (char*)&Hs[0][1][0], srow, ob1);
    }
    __syncthreads();

    int cur = 0;
    for (int t = t0; t < ntiles; t += G) {
        const int tn = t + G;
        const bool pf = stager && (tn < ntiles);
        uint4 xv0 = {0,0,0,0}, xv1 = {0,0,0,0}, gv0 = {0,0,0,0}, gv1 = {0,0,0,0};
        if (pf) {   // EARLY loads
            int grow = tn * 32 + srow; if (grow >= M) grow = M - 1;
            const uint4* ap = (const uint4*)(x + (size_t)grow * D + skf);
            xv0 = ap[0]; xv1 = ap[1];
            if (HASAGG) {
                const uint4* gp = (const uint4*)(agg + (size_t)grow * D + skf);
                gv0 = gp[0]; gv1 = gp[1];
            }
        }

        const bool dowork = (wgrp == 0) ||
                            (wgrp == 1 ? (t * 32 < Mroot) : (t * 32 < Mu));
        if (dowork) {
            char* hb = (char*)&Hs[cur][0][0];
            char* lb = (char*)&Hs[cur][1][0];
            f32x4 acc[2][4];
            #pragma unroll
            for (int ms = 0; ms < 2; ++ms)
                #pragma unroll
                for (int nf = 0; nf < 4; ++nf) acc[ms][nf] = (f32x4){0.f, 0.f, 0.f, 0.f};
            #pragma unroll
            for (int ks = 0; ks < 4; ++ks) {
                const int kb = ks * 64 + lg * 16;
                bf16x8 ah[2], al[2];
                #pragma unroll
                for (int ms = 0; ms < 2; ++ms) {
                    const int row = ms * 16 + li;
                    ah[ms] = *(const bf16x8*)haddr(hb, row, kb);
                    al[ms] = *(const bf16x8*)haddr(lb, row, kb);
                }
                #pragma unroll
                for (int nf = 0; nf < 4; ++nf)
                    #pragma unroll
                    for (int ms = 0; ms < 2; ++ms) {
                        acc[ms][nf] = __builtin_amdgcn_mfma_f32_16x16x32_bf16(bh[ks][nf], ah[ms], acc[ms][nf], 0, 0, 0);
                        acc[ms][nf] = __builtin_amdgcn_mfma_f32_16x16x32_bf16(bh[ks][nf], al[ms], acc[ms][nf], 0, 0, 0);
                        acc[ms][nf] = __builtin_amdgcn_mfma_f32_16x16x32_bf16(bl[ks][nf], ah[ms], acc[ms][nf], 0, 0, 0);
                    }
            }

            #pragma unroll
            for (int ms = 0; ms < 2; ++ms) {
                const int gr = t * 32 + ms * 16 + li;
                if (wgrp == 0) {
                    if (gr < M) {
                        unsigned short* yrow = y + (size_t)gr * D;
                        #pragma unroll
                        for (int nf = 0; nf < 4; ++nf) {
                            const int c0 = colbase + nf * 16 + lg * 4;
                            union { unsigned short s[4]; uint2 v; } pk;
                            #pragma unroll
                            for (int r = 0; r < 4; ++r) pk.s[r] = f2b(acc[ms][nf][r]);
                            *(uint2*)(yrow + c0) = pk.v;
                        }
                    }
                } else if (wgrp == 1) {
                    if (gr < Mroot) {
                        _Float16* xrow = x + (size_t)gr * D;
                        #pragma unroll
                        for (int nf = 0; nf < 4; ++nf) {
                            const int c0 = colbase + nf * 16 + lg * 4;
                            const float bb[4] = {bv[nf].x, bv[nf].y, bv[nf].z, bv[nf].w};
                            H4 pk;
                            #pragma unroll
                            for (int r = 0; r < 4; ++r) pk.h[r] = (_Float16)(acc[ms][nf][r] + bb[r]);
                            *(uint2*)(xrow + c0) = pk.u;
                        }
                    }
                } else {
                    if (gr < Mu) {
                        _Float16* urow = u + (size_t)gr * D;
                        #pragma unroll
                        for (int nf = 0; nf < 4; ++nf) {
                            const int c0 = colbase + nf * 16 + lg * 4;
                            float v[4];
                            #pragma unroll
                            for (int r = 0; r < 4; ++r) v[r] = acc[ms][nf][r];
                            if (UADD) {
                                H4 rd; rd.u = *(const uint2*)(urow + c0);
                                #pragma unroll
                                for (int r = 0; r < 4; ++r) v[r] += (float)rd.h[r];
                            }
                            H4 pk;
                            #pragma unroll
                            for (int r = 0; r < 4; ++r) pk.h[r] = (_Float16)v[r];
                            *(uint2*)(urow + c0) = pk.u;
                        }
                    }
                }
            }
        }

        if (pf) {   // LATE writes
            wsplit8<RELU_A, HASAGG>(xv0, gv0, (char*)&Hs[cur ^ 1][0][0],
                                    (char*)&Hs[cur ^ 1][1][0], srow, ob0);
            wsplit8<RELU_A, HASAGG>(xv1, gv1, (char*)&Hs[cur ^ 1][0][0],
                                    (char*)&Hs[cur ^ 1][1][0], srow, ob1);
        }
        __syncthreads();
        cur ^= 1;
    }
}

// ------------------------------------------------------------------
// CSR build
// ------------------------------------------------------------------
__global__ void hist_kernel(const int* __restrict__ dst, int* __restrict__ deg, int ne)
{
    int g = blockIdx.x * blockDim.x + threadIdx.x;
    if (g < ne) atomicAdd(&deg[dst[g]], 1);
}

__global__ __launch_bounds__(256, 1) void scan_blk(int* __restrict__ buf,
                                                   int* __restrict__ sums, int n)
{
    __shared__ int part[256];
    const int tid  = threadIdx.x;
    const int base = blockIdx.x * 1024 + tid * 4;
    int v0 = (base + 0 < n) ? buf[base + 0] : 0;
    int v1 = (base + 1 < n) ? buf[base + 1] : 0;
    int v2 = (base + 2 < n) ? buf[base + 2] : 0;
    int v3 = (base + 3 < n) ? buf[base + 3] : 0;
    const int t0 = v0, t1 = t0 + v1, t2 = t1 + v2, t3 = t2 + v3;
    part[tid] = t3;
    __syncthreads();
    #pragma unroll
    for (int off = 1; off < 256; off <<= 1) {
        int x = part[tid];
        if (tid >= off) x += part[tid - off];
        __syncthreads();
        part[tid] = x;
        __syncthreads();
    }
    if (tid == 255) sums[blockIdx.x] = part[255];
    const int excl = tid ? part[tid - 1] : 0;
    if (base + 0 < n) buf[base + 0] = excl;
    if (base + 1 < n) buf[base + 1] = excl + t0;
    if (base + 2 < n) buf[base + 2] = excl + t1;
    if (base + 3 < n) buf[base + 3] = excl + t2;
}

__global__ __launch_bounds__(256, 1) void scan_top(int* __restrict__ sums, int nb)
{
    __shared__ int part[256];
    const int tid = threadIdx.x;
    part[tid] = (tid < nb) ? sums[tid] : 0;
    __syncthreads();
    #pragma unroll
    for (int off = 1; off < 256; off <<= 1) {
        int x = part[tid];
        if (tid >= off) x += part[tid - off];
        __syncthreads();
        part[tid] = x;
        __syncthreads();
    }
    if (tid < nb) sums[tid] = tid ? part[tid - 1] : 0;
}

__global__ void scan_add(int* __restrict__ buf, const int* __restrict__ sums, int n)
{
    int i = blockIdx.x * blockDim.x + threadIdx.x;
    if (i < n) buf[i] += sums[i >> 10];
}

__global__ void fill_kernel(const int* __restrict__ src, const int* __restrict__ dst,
                            const int* __restrict__ etype,
                            int* __restrict__ cursor, int* __restrict__ edges, int ne)
{
    int e = blockIdx.x * blockDim.x + threadIdx.x;
    if (e < ne) {
        const int pos = atomicAdd(&cursor[dst[e]], 1);
        edges[pos] = (src[e] << 1) | (etype[e] & 1);
    }
}

// ------------------------------------------------------------------
// gather_agg: agg[i] = (1/max(deg,1)) * sum att[etype]*y[src]  (fp16 out)
// ------------------------------------------------------------------
__global__ __launch_bounds__(256, 2) void gather_agg(
    const int* __restrict__ cursor, const int* __restrict__ edges,
    const float* __restrict__ att, const unsigned short* __restrict__ y,
    _Float16* __restrict__ agg, int nn)
{
    const int gid  = blockIdx.x * 256 + threadIdx.x;
    const int node = gid >> 4;
    const int l    = gid & 15;
    if (node >= nn) return;
    const int end   = cursor[node];
    const int start = node ? cursor[node - 1] : 0;
    const float a0 = att[0], a1 = att[1];
    float s0[8] = {0,0,0,0,0,0,0,0}, s1[8] = {0,0,0,0,0,0,0,0};
    int j = start;
    for (; j + 2 <= end; j += 2) {
        const int p0 = edges[j], p1 = edges[j + 1];
        const float w0 = (p0 & 1) ? a1 : a0;
        const float w1 = (p1 & 1) ? a1 : a0;
        const uint4 va = ((const uint4*)(y + ((size_t)(p0 >> 1)) * D))[l];
        const uint4 vb = ((const uint4*)(y + ((size_t)(p1 >> 1)) * D))[l];
        const unsigned int wa[4] = {va.x, va.y, va.z, va.w};
        const unsigned int wb[4] = {vb.x, vb.y, vb.z, vb.w};
        #pragma unroll
        for (int q = 0; q < 4; ++q) {
            s0[q * 2 + 0] = fmaf(w0, b2f((unsigned short)(wa[q] & 0xFFFF)), s0[q * 2 + 0]);
            s0[q * 2 + 1] = fmaf(w0, b2f((unsigned short)(wa[q] >> 16)),    s0[q * 2 + 1]);
            s1[q * 2 + 0] = fmaf(w1, b2f((unsigned short)(wb[q] & 0xFFFF)), s1[q * 2 + 0]);
            s1[q * 2 + 1] = fmaf(w1, b2f((unsigned short)(wb[q] >> 16)),    s1[q * 2 + 1]);
        }
    }
    if (j < end) {
        const int p0 = edges[j];
        const float w0 = (p0 & 1) ? a1 : a0;
        const uint4 va = ((const uint4*)(y + ((size_t)(p0 >> 1)) * D))[l];
        const unsigned int wa[4] = {va.x, va.y, va.z, va.w};
        #pragma unroll
        for (int q = 0; q < 4; ++q) {
            s0[q * 2 + 0] = fmaf(w0, b2f((unsigned short)(wa[q] & 0xFFFF)), s0[q * 2 + 0]);
            s0[q * 2 + 1] = fmaf(w0, b2f((unsigned short)(wa[q] >> 16)),    s0[q * 2 + 1]);
        }
    }
    const float inv = 1.0f / fmaxf((float)(end - start), 1.0f);
    H8 o;
    #pragma unroll
    for (int q = 0; q < 8; ++q) o.h[q] = (_Float16)((s0[q] + s1[q]) * inv);
    *(uint4*)(agg + (size_t)node * D + l * 8) = o.u;
}

// ------------------------------------------------------------------
extern "C" void kernel_launch(void* const* d_in, const int* in_sizes, int n_in,
                              void* d_out, int out_size, void* d_ws, size_t ws_size,
                              hipStream_t stream)
{
    const float* varf      = (const float*)d_in[0];
    const float* conf      = (const float*)d_in[1];
    const int*   edge_src  = (const int*)d_in[5];
    const int*   edge_dst  = edge_src + NE;
    const int*   etype     = (const int*)d_in[6];
    const float* var_w1 = (const float*)d_in[8];
    const float* var_b1 = (const float*)d_in[9];
    const float* var_w2 = (const float*)d_in[10];
    const float* var_b2 = (const float*)d_in[11];
    const float* con_w1 = (const float*)d_in[12];
    const float* con_b1 = (const float*)d_in[13];
    const float* con_w2 = (const float*)d_in[14];
    const float* con_b2 = (const float*)d_in[15];
    const float* basisL[3] = {(const float*)d_in[16], (const float*)d_in[20], (const float*)d_in[24]};
    const float* attL[3]   = {(const float*)d_in[17], (const float*)d_in[21], (const float*)d_in[25]};
    const float* rootL[3]  = {(const float*)d_in[18], (const float*)d_in[22], (const float*)d_in[26]};
    const float* biasL[3]  = {(const float*)d_in[19], (const float*)d_in[23], (const float*)d_in[27]};
    const float* fc1_w = (const float*)d_in[28];
    const float* fc1_b = (const float*)d_in[29];
    const float* fc4_w = (const float*)d_in[30];
    const float* fc4_b = (const float*)d_in[31];

    // ---- workspace (assoc_var = arange(NV), assoc_con = NV+arange(NC)) ----
    const size_t XB  = (size_t)NN * D * 2;       // x fp16          51.2 MB
    const size_t YB  = (size_t)NN * D * 2;       // y bf16          51.2 MB
    const size_t AB  = (size_t)NN * D * 2;       // agg fp16        51.2 MB
    const size_t UB  = (size_t)NV * D * 2;       // u fp16          25.6 MB
    const size_t CUR = (size_t)NN * 4;
    const size_t EDG = (size_t)NE * 4;
    const size_t SUM = 4096;
    const size_t WT  = (size_t)12 * 32768 * 2;
    const size_t need = XB + YB + AB + UB + CUR + EDG + SUM + WT;   // ~183 MB
    if (ws_size < need) {
        hipMemsetAsync(d_out, 0, (size_t)out_size * sizeof(float), stream);
        return;
    }
    char* p = (char*)d_ws;
    _Float16*       x      = (_Float16*)p;       p += XB;
    unsigned short* y      = (unsigned short*)p; p += YB;
    _Float16*       agg    = (_Float16*)p;       p += AB;
    _Float16*       u      = (_Float16*)p;       p += UB;
    int*            cursor = (int*)p;            p += CUR;
    int*            edges  = (int*)p;            p += EDG;
    int*            sums   = (int*)p;            p += SUM;
    unsigned short* wt     = (unsigned short*)p;

    // out accumulated atomically by ugemmf -> zero each call (replay-safe)
    hipMemsetAsync(d_out, 0, (size_t)out_size * sizeof(float), stream);

    // ---- weight prep ----
    PrepArgs pa;
    pa.src[0] = basisL[0]; pa.src[1] = basisL[1]; pa.src[2] = basisL[2];
    pa.src[3] = rootL[0];  pa.src[4] = rootL[1];  pa.src[5] = rootL[2];
    pa.src[6] = fc1_w;                 pa.src[7] = fc1_w + 128 * 128;
    pa.src[8] = fc1_w + 2 * 128 * 128; pa.src[9] = fc1_w + 3 * 128 * 128;
    pa.src[10] = var_w2;               pa.src[11] = con_w2;
    prep_kernel<<<dim3(16, 12), 256, 0, stream>>>(pa, wt);

    // ---- CSR build ----
    hipMemsetAsync(cursor, 0, CUR, stream);
    hist_kernel<<<(NE + 255) / 256, 256, 0, stream>>>(edge_dst, cursor, NE);
    const int nblk = (NN + 1023) / 1024;
    scan_blk<<<nblk, 256, 0, stream>>>(cursor, sums, NN);
    scan_top<<<1, 256, 0, stream>>>(sums, nblk);
    scan_add<<<(NN + 255) / 256, 256, 0, stream>>>(cursor, sums, NN);
    fill_kernel<<<(NE + 255) / 256, 256, 0, stream>>>(edge_src, edge_dst, etype,
                                                      cursor, edges, NE);

    const int GM = 1024;   // gemm6/ugemmf: 4 blocks/CU
    const int GL = 1024;   // layer10: target 4 blocks/CU (384 thr, 6 waves)

    // ---- embeddings (fused hidden) -> x0 fp16 ----
    gemm6<2, false, false><<<GM, 256, 0, stream>>>(
        varf, nullptr, var_w1, var_b1, NV, wt + (size_t)10 * 32768, var_b2, x);
    gemm6<2, false, false><<<GM, 256, 0, stream>>>(
        conf, nullptr, con_w1, con_b1, NC, wt + (size_t)11 * 32768, con_b2,
        x + (size_t)NV * D);

    for (int l = 0; l < 3; ++l) {
        const unsigned short* wb_ = wt + (size_t)l * 32768;
        const unsigned short* wr_ = wt + (size_t)(3 + l) * 32768;
        const unsigned short* wu_ = wt + (size_t)(6 + l) * 32768;   // fc1 slice l
        const int mroot = (l == 2) ? NV : NN;
        const int gn    = (l == 2) ? NV : NN;
        if (l == 0)
            layer10<false, false, false><<<GL, 384, 0, stream>>>(
                x, nullptr, NN, mroot, wb_, wr_, wu_, biasL[0], y, u, NV);
        else
            layer10<true, true, true><<<GL, 384, 0, stream>>>(
                x, agg, NN, mroot, wb_, wr_, wu_, biasL[l], y, u, NV);
        gather_agg<<<(gn * 16 + 255) / 256, 256, 0, stream>>>(
            cursor, edges, attL[l], y, agg, gn);
    }

    // fused: u_final = u + relu(x+agg)@fc1_3 ; out = relu(u_final+fc1_b).fc4_w + fc4_b
    ugemmf<<<GM, 256, 0, stream>>>(x, agg, u, NV, wt + (size_t)9 * 32768,
                                   fc1_b, fc4_w, fc4_b, (float*)d_out);
}

// Round 19
// 412.162 us; speedup vs baseline: 3.3131x; 3.3131x over previous
//
#include <hip/hip_runtime.h>
#include <hip/hip_bf16.h>

#define D 128
#define NV 100000
#define NC 100000
#define NN 200000
#define NE 640000

typedef __attribute__((ext_vector_type(4))) float f32x4;
typedef __attribute__((ext_vector_type(8))) short bf16x8;

static __device__ __forceinline__ unsigned short f2b(float f) {
    __hip_bfloat16 h = __float2bfloat16(f);
    union { __hip_bfloat16 h; unsigned short u; } c; c.h = h; return c.u;
}
static __device__ __forceinline__ float b2f(unsigned short b) {
    union { unsigned int u; float f; } c; c.u = ((unsigned int)b) << 16; return c.f;
}

// split 8 fp32 -> hi/lo bf16x8 (residual ~2^-17 rel). ALL THREE MFMA
// products (Ah*Bh, Al*Bh, Ah*Bl) are required (2-MFMA fails accuracy).
template<bool RELU>
static __device__ __forceinline__ void split8v(const float f[8], bf16x8& ah, bf16x8& al)
{
    union { unsigned short s[8]; bf16x8 v; } ph, pl;
    #pragma unroll
    for (int j = 0; j < 8; ++j) {
        float x = RELU ? fmaxf(f[j], 0.f) : f[j];
        ph.s[j] = f2b(x);
        pl.s[j] = f2b(x - b2f(ph.s[j]));
    }
    ah = ph.v; al = pl.v;
}

union H8 { _Float16 h[8]; uint4 u; };
union H4 { _Float16 h[4]; uint2 u; };

// ------------------------------------------------------------------
// Weight prep -> fragment-major: out[(ks*4+lg)*128 + n][j 0..7]
// per matrix: hi 16384 ushorts | lo 16384.
// 0..2 basis1..3, 3..5 root1..3, 6..9 fc1 slices, 10 var_w2, 11 con_w2
// ------------------------------------------------------------------
struct PrepArgs { const float* src[12]; };

__global__ __launch_bounds__(256, 1) void prep_kernel(PrepArgs a, unsigned short* wt)
{
    const float* W = a.src[blockIdx.y];
    unsigned short* hi = wt + (size_t)blockIdx.y * 32768;
    unsigned short* lo = hi + 16384;
    const int o = blockIdx.x * 1024 + threadIdx.x * 4;
    const int slice = o >> 10;
    const int n     = (o >> 3) & 127;
    const int j0    = o & 7;
    union { unsigned short s[4]; unsigned long long u; } ph, pl;
    #pragma unroll
    for (int i = 0; i < 4; ++i) {
        const int k = slice * 8 + j0 + i;
        const float w = W[k * 128 + n];
        ph.s[i] = f2b(w);
        pl.s[i] = f2b(w - b2f(ph.s[i]));
    }
    *(unsigned long long*)&hi[o] = ph.u;
    *(unsigned long long*)&lo[o] = pl.u;
}

static __device__ __forceinline__ const bf16x8* wfrag(const unsigned short* wt,
                                                      int ks, int lg, int n)
{
    return (const bf16x8*)(wt + (((ks * 4 + lg) * 128) + n) * 8);
}

// LDS tile: pre-split bf16 [rows][128 k], XOR-swizzled.
static __device__ __forceinline__ char* haddr(char* base, int row, int byteoff)
{
    return base + row * 256 + (byteoff ^ ((row & 7) << 4));
}

// write 8 fp16-derived elems (x + optional agg) split into hi/lo LDS
template<bool RELU, bool HASAGG>
static __device__ __forceinline__ void wsplit8(uint4 xv, uint4 gv,
                                               char* hb, char* lb, int srow, int ob0)
{
    H8 a0; a0.u = xv;
    float f[8];
    #pragma unroll
    for (int j = 0; j < 8; ++j) f[j] = (float)a0.h[j];
    if (HASAGG) {
        H8 g0; g0.u = gv;
        #pragma unroll
        for (int j = 0; j < 8; ++j) f[j] += (float)g0.h[j];
    }
    bf16x8 h0, l0;
    split8v<RELU>(f, h0, l0);
    *(bf16x8*)(hb + srow * 256 + ob0) = h0;
    *(bf16x8*)(lb + srow * 256 + ob0) = l0;
}

// ------------------------------------------------------------------
// gemm6: C[M,128](fp16) (+)= op(xin[m]) @ W (+bias)
// AMODE: 0 = x fp16 ; 1 = x+agg fp16 ; 2 = embed fused hidden.
// 256 thr / 4 waves; wave owns 32 cols (B resident 64 VGPR).
// T14: next-tile loads issued BEFORE MFMA; split+write after epilogue.
// ------------------------------------------------------------------
template<int AMODE, bool RELU_A, bool ADD_C>
__global__ __launch_bounds__(256, 4) void gemm6(
    const void* A, const _Float16* __restrict__ agg,
    const float* __restrict__ w1, const float* __restrict__ b1, int M,
    const unsigned short* __restrict__ wt, const float* __restrict__ bias,
    _Float16* Cout)
{
    __shared__ unsigned short Hs[2][2][32 * 128];
    const int tid  = threadIdx.x;
    const int lane = tid & 63, wv = tid >> 6;
    const int li   = lane & 15, lg = lane >> 4;
    const int colbase = wv * 32;

    bf16x8 bh[4][2], bl[4][2];
    #pragma unroll
    for (int ks = 0; ks < 4; ++ks)
        #pragma unroll
        for (int nf = 0; nf < 2; ++nf) {
            const int n = colbase + nf * 16 + li;
            bh[ks][nf] = *wfrag(wt,         ks, lg, n);
            bl[ks][nf] = *wfrag(wt + 16384, ks, lg, n);
        }

    const int ntiles = (M + 31) / 32;
    const int G = gridDim.x;
    const int t0 = blockIdx.x;
    if (t0 >= ntiles) return;

    const int srow = tid >> 3;          // 0..31
    const int skf  = (tid & 7) * 16;    // 16 elems / thread
    const int sw   = (srow & 7) << 4;
    const int ob0  = (skf * 2) ^ sw;
    const int ob1  = (skf * 2 + 16) ^ sw;

    #define LOADT(TT, XV0, XV1, GV0, GV1, FV)                                    \
    {                                                                            \
        int grow = (TT) * 32 + srow; if (grow >= M) grow = M - 1;                \
        if (AMODE == 2) {                                                        \
            FV = *(const float2*)((const float*)A + (size_t)grow * 2);           \
        } else {                                                                 \
            const uint4* ap = (const uint4*)((const _Float16*)A + (size_t)grow * D + skf); \
            XV0 = ap[0]; XV1 = ap[1];                                            \
            if (AMODE == 1) {                                                    \
                const uint4* gp = (const uint4*)(agg + (size_t)grow * D + skf);  \
                GV0 = gp[0]; GV1 = gp[1];                                        \
            }                                                                    \
        }                                                                        \
    }
    #define WRITET(BUF, XV0, XV1, GV0, GV1, FV)                                  \
    {                                                                            \
        char* hb_ = (char*)&Hs[BUF][0][0];                                       \
        char* lb_ = (char*)&Hs[BUF][1][0];                                       \
        if (AMODE == 2) {                                                        \
            float f[16];                                                         \
            const float f0 = FV.x, f1 = FV.y;                                    \
            _Pragma("unroll")                                                    \
            for (int q = 0; q < 4; ++q) {                                        \
                const float4 wa = *(const float4*)(w1 + skf + q * 4);            \
                const float4 wb = *(const float4*)(w1 + 128 + skf + q * 4);      \
                const float4 bb = *(const float4*)(b1 + skf + q * 4);            \
                f[q*4+0] = fmaxf(fmaf(f0, wa.x, fmaf(f1, wb.x, bb.x)), 0.f);     \
                f[q*4+1] = fmaxf(fmaf(f0, wa.y, fmaf(f1, wb.y, bb.y)), 0.f);     \
                f[q*4+2] = fmaxf(fmaf(f0, wa.z, fmaf(f1, wb.z, bb.z)), 0.f);     \
                f[q*4+3] = fmaxf(fmaf(f0, wa.w, fmaf(f1, wb.w, bb.w)), 0.f);     \
            }                                                                    \
            bf16x8 h0, l0, h1, l1;                                               \
            split8v<RELU_A>(&f[0], h0, l0);                                     \
            split8v<RELU_A>(&f[8], h1, l1);                                     \
            char* hbr = hb_ + srow * 256; char* lbr = lb_ + srow * 256;          \
            *(bf16x8*)(hbr + ob0) = h0; *(bf16x8*)(hbr + ob1) = h1;              \
            *(bf16x8*)(lbr + ob0) = l0; *(bf16x8*)(lbr + ob1) = l1;              \
        } else {                                                                 \
            wsplit8<RELU_A, AMODE == 1>(XV0, GV0, hb_, lb_, srow, ob0);          \
            wsplit8<RELU_A, AMODE == 1>(XV1, GV1, hb_, lb_, srow, ob1);          \
        }                                                                        \
    }

    {   // prologue
        uint4 xv0 = {0,0,0,0}, xv1 = {0,0,0,0}, gv0 = {0,0,0,0}, gv1 = {0,0,0,0};
        float2 fv = {0, 0};
        LOADT(t0, xv0, xv1, gv0, gv1, fv);
        WRITET(0, xv0, xv1, gv0, gv1, fv);
    }
    __syncthreads();

    int cur = 0;
    for (int t = t0; t < ntiles; t += G) {
        const int tn = t + G;
        const bool pf = tn < ntiles;
        uint4 xv0 = {0,0,0,0}, xv1 = {0,0,0,0}, gv0 = {0,0,0,0}, gv1 = {0,0,0,0};
        float2 fv = {0, 0};
        if (pf) LOADT(tn, xv0, xv1, gv0, gv1, fv);   // EARLY

        char* hb = (char*)&Hs[cur][0][0];
        char* lb = (char*)&Hs[cur][1][0];
        f32x4 acc[2][2];
        #pragma unroll
        for (int ms = 0; ms < 2; ++ms)
            #pragma unroll
            for (int nf = 0; nf < 2; ++nf) acc[ms][nf] = (f32x4){0.f, 0.f, 0.f, 0.f};
        #pragma unroll
        for (int ks = 0; ks < 4; ++ks) {
            const int kb = ks * 64 + lg * 16;
            bf16x8 ah[2], al[2];
            #pragma unroll
            for (int ms = 0; ms < 2; ++ms) {
                const int row = ms * 16 + li;
                ah[ms] = *(const bf16x8*)haddr(hb, row, kb);
                al[ms] = *(const bf16x8*)haddr(lb, row, kb);
            }
            #pragma unroll
            for (int nf = 0; nf < 2; ++nf)
                #pragma unroll
                for (int ms = 0; ms < 2; ++ms) {
                    acc[ms][nf] = __builtin_amdgcn_mfma_f32_16x16x32_bf16(bh[ks][nf], ah[ms], acc[ms][nf], 0, 0, 0);
                    acc[ms][nf] = __builtin_amdgcn_mfma_f32_16x16x32_bf16(bh[ks][nf], al[ms], acc[ms][nf], 0, 0, 0);
                    acc[ms][nf] = __builtin_amdgcn_mfma_f32_16x16x32_bf16(bl[ks][nf], ah[ms], acc[ms][nf], 0, 0, 0);
                }
        }

        #pragma unroll
        for (int ms = 0; ms < 2; ++ms) {
            const int grow = t * 32 + ms * 16 + li;
            if (grow < M) {
                _Float16* crow = Cout + (size_t)grow * D;
                #pragma unroll
                for (int nf = 0; nf < 2; ++nf) {
                    const int c0 = colbase + nf * 16 + lg * 4;
                    float v[4];
                    #pragma unroll
                    for (int r = 0; r < 4; ++r) v[r] = acc[ms][nf][r];
                    if (bias) {
                        const float4 b = *(const float4*)(bias + c0);
                        v[0] += b.x; v[1] += b.y; v[2] += b.z; v[3] += b.w;
                    }
                    if (ADD_C) {
                        H4 rd; rd.u = *(const uint2*)(crow + c0);
                        #pragma unroll
                        for (int r = 0; r < 4; ++r) v[r] += (float)rd.h[r];
                    }
                    H4 pk;
                    #pragma unroll
                    for (int r = 0; r < 4; ++r) pk.h[r] = (_Float16)v[r];
                    *(uint2*)(crow + c0) = pk.u;
                }
            }
        }

        if (pf) WRITET(cur ^ 1, xv0, xv1, gv0, gv1, fv);   // LATE
        __syncthreads();
        cur ^= 1;
    }
    #undef LOADT
    #undef WRITET
}

// ------------------------------------------------------------------
// layer6: xin = x (+agg) fp16 (shared pre-split LDS tile, 32-row tiles)
//  waves 0-3 : y    = op(xin)@basis   (bf16, rows < M)
//  waves 4-7 : x    = op(xin)@root+b  (fp16, rows < Mroot)
//  waves 8-11: u (+)= op(xin)@fc1_l   (fp16, rows < Mu)
// 768 thr; stagers = threads 0-511; T14 load-early/write-late.
// GL=256 (1 block/CU persistent) is the empirical best configuration.
// ------------------------------------------------------------------
template<bool RELU_A, bool HASAGG, bool UADD>
__global__ __launch_bounds__(768, 3) void layer6(
    _Float16* x, const _Float16* __restrict__ agg, int M, int Mroot,
    const unsigned short* __restrict__ wtb, const unsigned short* __restrict__ wtr,
    const unsigned short* __restrict__ wtu, const float* __restrict__ bias,
    unsigned short* __restrict__ y, _Float16* __restrict__ u, int Mu)
{
    __shared__ unsigned short Hs[2][2][32 * 128];
    const int tid  = threadIdx.x;
    const int lane = tid & 63, wv = tid >> 6;      // 0..11
    const int li   = lane & 15, lg = lane >> 4;
    const int wgrp = wv >> 2;                      // 0 basis, 1 root, 2 u
    const int colbase = (wv & 3) * 32;
    const unsigned short* wsel = (wgrp == 0) ? wtb : (wgrp == 1) ? wtr : wtu;

    bf16x8 bh[4][2], bl[4][2];
    #pragma unroll
    for (int ks = 0; ks < 4; ++ks)
        #pragma unroll
        for (int nf = 0; nf < 2; ++nf) {
            const int n = colbase + nf * 16 + li;
            bh[ks][nf] = *wfrag(wsel,         ks, lg, n);
            bl[ks][nf] = *wfrag(wsel + 16384, ks, lg, n);
        }
    float4 bv[2] = {{0,0,0,0},{0,0,0,0}};
    if (wgrp == 1) {
        bv[0] = *(const float4*)(bias + colbase + 0  + lg * 4);
        bv[1] = *(const float4*)(bias + colbase + 16 + lg * 4);
    }

    const int ntiles = (M + 31) / 32;
    const int G = gridDim.x;
    const int t0 = blockIdx.x;
    if (t0 >= ntiles) return;

    const bool stager = tid < 512;
    const int srow = (tid & 511) >> 4;   // 0..31
    const int skf  = (tid & 15) * 8;     // 8 fp16 / thread
    const int sw   = (srow & 7) << 4;
    const int ob0  = (skf * 2) ^ sw;

    if (stager) {   // prologue
        int grow = t0 * 32 + srow; if (grow >= M) grow = M - 1;
        uint4 xv = *(const uint4*)(x + (size_t)grow * D + skf);
        uint4 gv = {0,0,0,0};
        if (HASAGG) gv = *(const uint4*)(agg + (size_t)grow * D + skf);
        wsplit8<RELU_A, HASAGG>(xv, gv, (char*)&Hs[0][0][0], (char*)&Hs[0][1][0], srow, ob0);
    }
    __syncthreads();

    int cur = 0;
    for (int t = t0; t < ntiles; t += G) {
        const int tn = t + G;
        const bool pf = stager && (tn < ntiles);
        uint4 xv = {0,0,0,0}, gv = {0,0,0,0};
        if (pf) {   // EARLY loads: hide under MFMA + epilogue
            int grow = tn * 32 + srow; if (grow >= M) grow = M - 1;
            xv = *(const uint4*)(x + (size_t)grow * D + skf);
            if (HASAGG) gv = *(const uint4*)(agg + (size_t)grow * D + skf);
        }

        char* hb = (char*)&Hs[cur][0][0];
        char* lb = (char*)&Hs[cur][1][0];
        f32x4 acc[2][2];
        #pragma unroll
        for (int ms = 0; ms < 2; ++ms)
            #pragma unroll
            for (int nf = 0; nf < 2; ++nf) acc[ms][nf] = (f32x4){0.f, 0.f, 0.f, 0.f};
        #pragma unroll
        for (int ks = 0; ks < 4; ++ks) {
            const int kb = ks * 64 + lg * 16;
            bf16x8 ah[2], al[2];
            #pragma unroll
            for (int ms = 0; ms < 2; ++ms) {
                const int row = ms * 16 + li;
                ah[ms] = *(const bf16x8*)haddr(hb, row, kb);
                al[ms] = *(const bf16x8*)haddr(lb, row, kb);
            }
            #pragma unroll
            for (int nf = 0; nf < 2; ++nf)
                #pragma unroll
                for (int ms = 0; ms < 2; ++ms) {
                    acc[ms][nf] = __builtin_amdgcn_mfma_f32_16x16x32_bf16(bh[ks][nf], ah[ms], acc[ms][nf], 0, 0, 0);
                    acc[ms][nf] = __builtin_amdgcn_mfma_f32_16x16x32_bf16(bh[ks][nf], al[ms], acc[ms][nf], 0, 0, 0);
                    acc[ms][nf] = __builtin_amdgcn_mfma_f32_16x16x32_bf16(bl[ks][nf], ah[ms], acc[ms][nf], 0, 0, 0);
                }
        }

        #pragma unroll
        for (int ms = 0; ms < 2; ++ms) {
            const int grow = t * 32 + ms * 16 + li;
            if (wgrp == 0) {
                if (grow < M) {
                    unsigned short* yrow = y + (size_t)grow * D;
                    #pragma unroll
                    for (int nf = 0; nf < 2; ++nf) {
                        const int c0 = colbase + nf * 16 + lg * 4;
                        union { unsigned short s[4]; uint2 v; } pk;
                        #pragma unroll
                        for (int r = 0; r < 4; ++r) pk.s[r] = f2b(acc[ms][nf][r]);
                        *(uint2*)(yrow + c0) = pk.v;
                    }
                }
            } else if (wgrp == 1) {
                if (grow < Mroot) {
                    _Float16* xrow = x + (size_t)grow * D;
                    #pragma unroll
                    for (int nf = 0; nf < 2; ++nf) {
                        const int c0 = colbase + nf * 16 + lg * 4;
                        const float bb[4] = {bv[nf].x, bv[nf].y, bv[nf].z, bv[nf].w};
                        H4 pk;
                        #pragma unroll
                        for (int r = 0; r < 4; ++r) pk.h[r] = (_Float16)(acc[ms][nf][r] + bb[r]);
                        *(uint2*)(xrow + c0) = pk.u;
                    }
                }
            } else {
                if (grow < Mu) {
                    _Float16* urow = u + (size_t)grow * D;
                    #pragma unroll
                    for (int nf = 0; nf < 2; ++nf) {
                        const int c0 = colbase + nf * 16 + lg * 4;
                        float v[4];
                        #pragma unroll
                        for (int r = 0; r < 4; ++r) v[r] = acc[ms][nf][r];
                        if (UADD) {
                            H4 rd; rd.u = *(const uint2*)(urow + c0);
                            #pragma unroll
                            for (int r = 0; r < 4; ++r) v[r] += (float)rd.h[r];
                        }
                        H4 pk;
                        #pragma unroll
                        for (int r = 0; r < 4; ++r) pk.h[r] = (_Float16)v[r];
                        *(uint2*)(urow + c0) = pk.u;
                    }
                }
            }
        }

        if (pf)   // LATE write
            wsplit8<RELU_A, HASAGG>(xv, gv, (char*)&Hs[cur ^ 1][0][0],
                                    (char*)&Hs[cur ^ 1][1][0], srow, ob0);
        __syncthreads();
        cur ^= 1;
    }
}

// ------------------------------------------------------------------
// CSR build
// ------------------------------------------------------------------
__global__ void hist_kernel(const int* __restrict__ dst, int* __restrict__ deg, int ne)
{
    int g = blockIdx.x * blockDim.x + threadIdx.x;
    if (g < ne) atomicAdd(&deg[dst[g]], 1);
}

__global__ __launch_bounds__(256, 1) void scan_blk(int* __restrict__ buf,
                                                   int* __restrict__ sums, int n)
{
    __shared__ int part[256];
    const int tid  = threadIdx.x;
    const int base = blockIdx.x * 1024 + tid * 4;
    int v0 = (base + 0 < n) ? buf[base + 0] : 0;
    int v1 = (base + 1 < n) ? buf[base + 1] : 0;
    int v2 = (base + 2 < n) ? buf[base + 2] : 0;
    int v3 = (base + 3 < n) ? buf[base + 3] : 0;
    const int t0 = v0, t1 = t0 + v1, t2 = t1 + v2, t3 = t2 + v3;
    part[tid] = t3;
    __syncthreads();
    #pragma unroll
    for (int off = 1; off < 256; off <<= 1) {
        int x = part[tid];
        if (tid >= off) x += part[tid - off];
        __syncthreads();
        part[tid] = x;
        __syncthreads();
    }
    if (tid == 255) sums[blockIdx.x] = part[255];
    const int excl = tid ? part[tid - 1] : 0;
    if (base + 0 < n) buf[base + 0] = excl;
    if (base + 1 < n) buf[base + 1] = excl + t0;
    if (base + 2 < n) buf[base + 2] = excl + t1;
    if (base + 3 < n) buf[base + 3] = excl + t2;
}

__global__ __launch_bounds__(256, 1) void scan_top(int* __restrict__ sums, int nb)
{
    __shared__ int part[256];
    const int tid = threadIdx.x;
    part[tid] = (tid < nb) ? sums[tid] : 0;
    __syncthreads();
    #pragma unroll
    for (int off = 1; off < 256; off <<= 1) {
        int x = part[tid];
        if (tid >= off) x += part[tid - off];
        __syncthreads();
        part[tid] = x;
        __syncthreads();
    }
    if (tid < nb) sums[tid] = tid ? part[tid - 1] : 0;
}

__global__ void scan_add(int* __restrict__ buf, const int* __restrict__ sums, int n)
{
    int i = blockIdx.x * blockDim.x + threadIdx.x;
    if (i < n) buf[i] += sums[i >> 10];
}

__global__ void fill_kernel(const int* __restrict__ src, const int* __restrict__ dst,
                            const int* __restrict__ etype,
                            int* __restrict__ cursor, int* __restrict__ edges, int ne)
{
    int e = blockIdx.x * blockDim.x + threadIdx.x;
    if (e < ne) {
        const int pos = atomicAdd(&cursor[dst[e]], 1);
        edges[pos] = (src[e] << 1) | (etype[e] & 1);
    }
}

// ------------------------------------------------------------------
// gather_agg: agg[i] = (1/max(deg,1)) * sum att[etype]*y[src]  (fp16 out)
// ------------------------------------------------------------------
__global__ __launch_bounds__(256, 2) void gather_agg(
    const int* __restrict__ cursor, const int* __restrict__ edges,
    const float* __restrict__ att, const unsigned short* __restrict__ y,
    _Float16* __restrict__ agg, int nn)
{
    const int gid  = blockIdx.x * 256 + threadIdx.x;
    const int node = gid >> 4;
    const int l    = gid & 15;
    if (node >= nn) return;
    const int end   = cursor[node];
    const int start = node ? cursor[node - 1] : 0;
    const float a0 = att[0], a1 = att[1];
    float s0[8] = {0,0,0,0,0,0,0,0}, s1[8] = {0,0,0,0,0,0,0,0};
    int j = start;
    for (; j + 2 <= end; j += 2) {
        const int p0 = edges[j], p1 = edges[j + 1];
        const float w0 = (p0 & 1) ? a1 : a0;
        const float w1 = (p1 & 1) ? a1 : a0;
        const uint4 va = ((const uint4*)(y + ((size_t)(p0 >> 1)) * D))[l];
        const uint4 vb = ((const uint4*)(y + ((size_t)(p1 >> 1)) * D))[l];
        const unsigned int wa[4] = {va.x, va.y, va.z, va.w};
        const unsigned int wb[4] = {vb.x, vb.y, vb.z, vb.w};
        #pragma unroll
        for (int q = 0; q < 4; ++q) {
            s0[q * 2 + 0] = fmaf(w0, b2f((unsigned short)(wa[q] & 0xFFFF)), s0[q * 2 + 0]);
            s0[q * 2 + 1] = fmaf(w0, b2f((unsigned short)(wa[q] >> 16)),    s0[q * 2 + 1]);
            s1[q * 2 + 0] = fmaf(w1, b2f((unsigned short)(wb[q] & 0xFFFF)), s1[q * 2 + 0]);
            s1[q * 2 + 1] = fmaf(w1, b2f((unsigned short)(wb[q] >> 16)),    s1[q * 2 + 1]);
        }
    }
    if (j < end) {
        const int p0 = edges[j];
        const float w0 = (p0 & 1) ? a1 : a0;
        const uint4 va = ((const uint4*)(y + ((size_t)(p0 >> 1)) * D))[l];
        const unsigned int wa[4] = {va.x, va.y, va.z, va.w};
        #pragma unroll
        for (int q = 0; q < 4; ++q) {
            s0[q * 2 + 0] = fmaf(w0, b2f((unsigned short)(wa[q] & 0xFFFF)), s0[q * 2 + 0]);
            s0[q * 2 + 1] = fmaf(w0, b2f((unsigned short)(wa[q] >> 16)),    s0[q * 2 + 1]);
        }
    }
    const float inv = 1.0f / fmaxf((float)(end - start), 1.0f);
    H8 o;
    #pragma unroll
    for (int q = 0; q < 8; ++q) o.h[q] = (_Float16)((s0[q] + s1[q]) * inv);
    *(uint4*)(agg + (size_t)node * D + l * 8) = o.u;
}

// ------------------------------------------------------------------
// final: out[i] = relu(u[i]+fc1_b) . fc4_w + fc4_b   (u fp16)
// ------------------------------------------------------------------
__global__ void final_kernel(
    const _Float16* __restrict__ u, const float* __restrict__ fc1_b,
    const float* __restrict__ fc4_w, const float* __restrict__ fc4_b,
    float* __restrict__ out, int n)
{
    int gid = blockIdx.x * blockDim.x + threadIdx.x;
    int row = gid >> 5, lane = gid & 31;
    if (row >= n) return;
    H4 uv; uv.u = ((const uint2*)(u + (size_t)row * D))[lane];
    float4 b = ((const float4*)fc1_b)[lane];
    float4 w = ((const float4*)fc4_w)[lane];
    float s = fmaxf((float)uv.h[0] + b.x, 0.f) * w.x
            + fmaxf((float)uv.h[1] + b.y, 0.f) * w.y
            + fmaxf((float)uv.h[2] + b.z, 0.f) * w.z
            + fmaxf((float)uv.h[3] + b.w, 0.f) * w.w;
    #pragma unroll
    for (int off = 1; off < 32; off <<= 1) s += __shfl_xor(s, off);
    if (lane == 0) out[row] = s + fc4_b[0];
}

// ------------------------------------------------------------------
extern "C" void kernel_launch(void* const* d_in, const int* in_sizes, int n_in,
                              void* d_out, int out_size, void* d_ws, size_t ws_size,
                              hipStream_t stream)
{
    const float* varf      = (const float*)d_in[0];
    const float* conf      = (const float*)d_in[1];
    const int*   edge_src  = (const int*)d_in[5];
    const int*   edge_dst  = edge_src + NE;
    const int*   etype     = (const int*)d_in[6];
    const float* var_w1 = (const float*)d_in[8];
    const float* var_b1 = (const float*)d_in[9];
    const float* var_w2 = (const float*)d_in[10];
    const float* var_b2 = (const float*)d_in[11];
    const float* con_w1 = (const float*)d_in[12];
    const float* con_b1 = (const float*)d_in[13];
    const float* con_w2 = (const float*)d_in[14];
    const float* con_b2 = (const float*)d_in[15];
    const float* basisL[3] = {(const float*)d_in[16], (const float*)d_in[20], (const float*)d_in[24]};
    const float* attL[3]   = {(const float*)d_in[17], (const float*)d_in[21], (const float*)d_in[25]};
    const float* rootL[3]  = {(const float*)d_in[18], (const float*)d_in[22], (const float*)d_in[26]};
    const float* biasL[3]  = {(const float*)d_in[19], (const float*)d_in[23], (const float*)d_in[27]};
    const float* fc1_w = (const float*)d_in[28];
    const float* fc1_b = (const float*)d_in[29];
    const float* fc4_w = (const float*)d_in[30];
    const float* fc4_b = (const float*)d_in[31];

    // ---- workspace (assoc_var = arange(NV), assoc_con = NV+arange(NC)) ----
    const size_t XB  = (size_t)NN * D * 2;       // x fp16          51.2 MB
    const size_t YB  = (size_t)NN * D * 2;       // y bf16          51.2 MB
    const size_t AB  = (size_t)NN * D * 2;       // agg fp16        51.2 MB
    const size_t UB  = (size_t)NV * D * 2;       // u fp16          25.6 MB
    const size_t CUR = (size_t)NN * 4;
    const size_t EDG = (size_t)NE * 4;
    const size_t SUM = 4096;
    const size_t WT  = (size_t)12 * 32768 * 2;
    const size_t need = XB + YB + AB + UB + CUR + EDG + SUM + WT;   // ~183 MB
    if (ws_size < need) {
        hipMemsetAsync(d_out, 0, (size_t)out_size * sizeof(float), stream);
        return;
    }
    char* p = (char*)d_ws;
    _Float16*       x      = (_Float16*)p;       p += XB;
    unsigned short* y      = (unsigned short*)p; p += YB;
    _Float16*       agg    = (_Float16*)p;       p += AB;
    _Float16*       u      = (_Float16*)p;       p += UB;
    int*            cursor = (int*)p;            p += CUR;
    int*            edges  = (int*)p;            p += EDG;
    int*            sums   = (int*)p;            p += SUM;
    unsigned short* wt     = (unsigned short*)p;

    // ---- weight prep ----
    PrepArgs pa;
    pa.src[0] = basisL[0]; pa.src[1] = basisL[1]; pa.src[2] = basisL[2];
    pa.src[3] = rootL[0];  pa.src[4] = rootL[1];  pa.src[5] = rootL[2];
    pa.src[6] = fc1_w;                 pa.src[7] = fc1_w + 128 * 128;
    pa.src[8] = fc1_w + 2 * 128 * 128; pa.src[9] = fc1_w + 3 * 128 * 128;
    pa.src[10] = var_w2;               pa.src[11] = con_w2;
    prep_kernel<<<dim3(16, 12), 256, 0, stream>>>(pa, wt);

    // ---- CSR build ----
    hipMemsetAsync(cursor, 0, CUR, stream);
    hist_kernel<<<(NE + 255) / 256, 256, 0, stream>>>(edge_dst, cursor, NE);
    const int nblk = (NN + 1023) / 1024;
    scan_blk<<<nblk, 256, 0, stream>>>(cursor, sums, NN);
    scan_top<<<1, 256, 0, stream>>>(sums, nblk);
    scan_add<<<(NN + 255) / 256, 256, 0, stream>>>(cursor, sums, NN);
    fill_kernel<<<(NE + 255) / 256, 256, 0, stream>>>(edge_src, edge_dst, etype,
                                                      cursor, edges, NE);

    const int GM = 1024;   // gemm6: 4 blocks/CU
    const int GL = 256;    // layer6: 1 block/CU persistent (empirical best)

    // ---- embeddings (fused hidden) -> x0 fp16 ----
    gemm6<2, false, false><<<GM, 256, 0, stream>>>(
        varf, nullptr, var_w1, var_b1, NV, wt + (size_t)10 * 32768, var_b2, x);
    gemm6<2, false, false><<<GM, 256, 0, stream>>>(
        conf, nullptr, con_w1, con_b1, NC, wt + (size_t)11 * 32768, con_b2,
        x + (size_t)NV * D);

    for (int l = 0; l < 3; ++l) {
        const unsigned short* wb_ = wt + (size_t)l * 32768;
        const unsigned short* wr_ = wt + (size_t)(3 + l) * 32768;
        const unsigned short* wu_ = wt + (size_t)(6 + l) * 32768;   // fc1 slice l
        const int mroot = (l == 2) ? NV : NN;
        const int gn    = (l == 2) ? NV : NN;
        if (l == 0)
            layer6<false, false, false><<<GL, 768, 0, stream>>>(
                x, nullptr, NN, mroot, wb_, wr_, wu_, biasL[0], y, u, NV);
        else
            layer6<true, true, true><<<GL, 768, 0, stream>>>(
                x, agg, NN, mroot, wb_, wr_, wu_, biasL[l], y, u, NV);
        gather_agg<<<(gn * 16 + 255) / 256, 256, 0, stream>>>(
            cursor, edges, attL[l], y, agg, gn);
    }

    // u += relu(x_3 = x+agg)[0:NV] @ fc1 slice 3
    gemm6<1, true, true><<<GM, 256, 0, stream>>>(
        x, agg, nullptr, nullptr, NV, wt + (size_t)9 * 32768, nullptr, u);

    final_kernel<<<(NV * 32 + 255) / 256, 256, 0, stream>>>(
        u, fc1_b, fc4_w, fc4_b, (float*)d_out, NV);
}